// Round 2
// baseline (37160.974 us; speedup 1.0000x reference)
//
#include <hip/hip_runtime.h>
#include <hip/hip_bf16.h>
#include <stdint.h>

typedef short short8 __attribute__((ext_vector_type(8)));
typedef float f32x4  __attribute__((ext_vector_type(4)));
typedef float fvec4  __attribute__((ext_vector_type(4)));

#define SCOPE_AGENT __HIP_MEMORY_SCOPE_AGENT
#define MFMA(a,b,c) __builtin_amdgcn_mfma_f32_16x16x32_bf16((a),(b),(c),0,0,0)

constexpr int nB = 64, nT = 1024, nD = 256, nH = 512, nO = 256;
constexpr int SLOT_ELEMS = 64 * 1024;                 // 64 rows x (512 hi | 512 lo) bf16
constexpr size_t SLOT_BYTES = (size_t)SLOT_ELEMS * 2; // 128 KiB
constexpr size_t RING_OFF = 4096;
constexpr int NEG = -0x40000000;

__device__ __forceinline__ float sigm(float x){ return 1.f/(1.f + __expf(-x)); }

// fp32 -> (hi, lo) bf16 pair, 8 contiguous elements
__device__ __forceinline__ void cvt8(const float* p, short8& hi, short8& lo){
  fvec4 a = *(const fvec4*)p;
  fvec4 b = *(const fvec4*)(p + 4);
  #pragma unroll
  for (int j = 0; j < 8; j++){
    float v = (j < 4) ? a[j] : b[j-4];
    __hip_bfloat16 h = __float2bfloat16(v);
    float r = v - __bfloat162float(h);
    hi[j] = (short)__bfloat16_as_ushort(h);
    lo[j] = (short)__bfloat16_as_ushort(__float2bfloat16(r));
  }
}

__device__ __forceinline__ unsigned pack2(float a, float b){
  unsigned ha = __bfloat16_as_ushort(__float2bfloat16(a));
  unsigned hb = __bfloat16_as_ushort(__float2bfloat16(b));
  return ha | (hb << 16);
}
__device__ __forceinline__ unsigned pack2lo(float a, float b){
  float ra = a - __bfloat162float(__float2bfloat16(a));
  float rb = b - __bfloat162float(__float2bfloat16(b));
  return pack2(ra, rb);
}

// agent-scope (LLC-coherent) 16B load = two 8B atomic loads; required because
// ring slots are rewritten within a launch (plain loads could hit stale L1/L2).
__device__ __forceinline__ short8 aload16(const short* p){
  union { unsigned long long u[2]; short8 v; } r;
  const unsigned long long* q = (const unsigned long long*)p;
  r.u[0] = __hip_atomic_load(q,     __ATOMIC_RELAXED, SCOPE_AGENT);
  r.u[1] = __hip_atomic_load(q + 1, __ATOMIC_RELAXED, SCOPE_AGENT);
  return r.v;
}

// all 64 lanes poll 64 flags (lanes 0..31: layer-0 flags, 32..63: layer-1)
__device__ __forceinline__ void poll(const int* fb, int t0, int t1, int& dead){
  if (dead) return;
  int lid = threadIdx.x & 63;
  int tgt = (lid < 32) ? t0 : t1;
  const int* p = fb + lid;
  int guard = 0;
  for(;;){
    int v = __hip_atomic_load(p, __ATOMIC_RELAXED, SCOPE_AGENT);
    if (__all(v >= tgt)) break;
    if (++guard > (1<<17)) { dead = 1; break; }    // fail-fast, never hang
  }
  __builtin_amdgcn_fence(__ATOMIC_ACQUIRE, "agent");
}

__global__ __launch_bounds__(256, 1) void lstm_kernel(
    const float* __restrict__ x,
    const float* __restrict__ Wih0, const float* __restrict__ Whh0,
    const float* __restrict__ bih0, const float* __restrict__ bhh0,
    const float* __restrict__ Wih1, const float* __restrict__ Whh1,
    const float* __restrict__ bih1, const float* __restrict__ bhh1,
    const float* __restrict__ fcw, const float* __restrict__ fcb,
    float* __restrict__ out,
    short* __restrict__ h1r, short* __restrict__ h2r,
    float* __restrict__ h2last, int* __restrict__ flags)
{
  const int bid   = blockIdx.x;
  const int layer = bid & 1;
  const int bs    = (bid >> 1) & 3;   // batch slice (16 rows)
  const int ns    = bid >> 3;         // H-chunk (16 cols)
  const int tid   = threadIdx.x;
  const int w     = tid >> 6;         // wave = gate (i,f,g,o)
  const int l     = tid & 63;
  const int lm    = l & 15;
  const int ke    = (l >> 4) << 3;    // k offset within K=32 step

  int* fb     = flags + (bs << 6);
  int* myflag = fb + (layer << 5) + ns;

  __shared__ float glds[4][16][16];

  const int gcol = (w << 9) + (ns << 4) + lm;   // gate row in [0,2048)
  const int brow = (bs << 4) + lm;              // batch row (A fragment)
  const int bl   = tid >> 4, jj = tid & 15;     // per-thread cell (row, col)
  const int hcolbase = ns << 4;

  int   dead  = 0;
  float c_reg = 0.f;
  float bias  = layer == 0 ? bih0[gcol] + bhh0[gcol] : bih1[gcol] + bhh1[gcol];

  // ---- cell update macro (gates -> c,h -> hi/lo bf16 ring store -> flag) ----
  #define CELL(ACC, SLOTBASE, T, LAST)                                          \
  {                                                                             \
    _Pragma("unroll")                                                           \
    for (int r = 0; r < 4; r++) glds[w][((l>>4)<<2)+r][lm] = (ACC)[r] + bias;   \
    __syncthreads();                                                            \
    float gi = glds[0][bl][jj], gf = glds[1][bl][jj];                           \
    float gg = glds[2][bl][jj], go = glds[3][bl][jj];                           \
    float cn = sigm(gf)*c_reg + sigm(gi)*tanhf(gg);                             \
    c_reg = cn;                                                                 \
    float hn  = sigm(go)*tanhf(cn);                                             \
    float hn2 = __shfl_down(hn, 1);                                             \
    if (!(jj & 1)){                                                             \
      short* p = (SLOTBASE) + bl*1024 + hcolbase + jj;                          \
      __hip_atomic_store((unsigned*)p,       pack2(hn,hn2),   __ATOMIC_RELAXED, SCOPE_AGENT); \
      __hip_atomic_store((unsigned*)(p+512), pack2lo(hn,hn2), __ATOMIC_RELAXED, SCOPE_AGENT); \
    }                                                                           \
    if (LAST)                                                                   \
      __hip_atomic_store(h2last + (size_t)((bs<<4)+bl)*nH + hcolbase + jj, hn,  \
                         __ATOMIC_RELAXED, SCOPE_AGENT);                        \
    __syncthreads();  /* vmcnt(0) drain of all waves' stores */                 \
    if (tid == 0) __hip_atomic_store(myflag, (T), __ATOMIC_RELEASE, SCOPE_AGENT); \
  }

  if (layer == 0){
    short8 wxh[8], wxl[8], whh[16], whl[16];      // hi/lo weight frags in VGPRs
    #pragma unroll
    for (int kk = 0; kk < 8;  kk++) cvt8(Wih0 + (size_t)gcol*nD + kk*32 + ke, wxh[kk], wxl[kk]);
    #pragma unroll
    for (int kk = 0; kk < 16; kk++) cvt8(Whh0 + (size_t)gcol*nH + kk*32 + ke, whh[kk], whl[kk]);

    // prologue: x-projection for t=0
    f32x4 xacc = {0.f,0.f,0.f,0.f};
    {
      const float* xb = x + ((size_t)brow*nT + 0)*nD + ke;
      #pragma unroll
      for (int kk = 0; kk < 8; kk++){
        short8 xh, xl; cvt8(xb + kk*32, xh, xl);
        xacc = MFMA(xh, wxh[kk], xacc);
        xacc = MFMA(xl, wxh[kk], xacc);
        xacc = MFMA(xh, wxl[kk], xacc);
      }
    }

    for (int t = 0; t < nT; t++){
      poll(fb, t-1, t-8, dead);                    // L0 peers t-1; L1 ring backpressure
      f32x4 acc = xacc;
      const short* hb = h1r + (size_t)((t+7)&7)*SLOT_ELEMS + brow*1024;
      #pragma unroll
      for (int kk = 0; kk < 16; kk++){
        short8 hh = aload16(hb + kk*32 + ke);
        short8 hl = aload16(hb + 512 + kk*32 + ke);
        acc = MFMA(hh, whh[kk], acc);
        acc = MFMA(hl, whh[kk], acc);
        acc = MFMA(hh, whl[kk], acc);
      }
      CELL(acc, h1r + (size_t)(t&7)*SLOT_ELEMS + (bs<<4)*1024, t, 0);
      if (t + 1 < nT){                             // x-proj for t+1 off critical path
        xacc = (f32x4){0.f,0.f,0.f,0.f};
        const float* xb = x + ((size_t)brow*nT + (t+1))*nD + ke;
        #pragma unroll
        for (int kk = 0; kk < 8; kk++){
          short8 xh, xl; cvt8(xb + kk*32, xh, xl);
          xacc = MFMA(xh, wxh[kk], xacc);
          xacc = MFMA(xl, wxh[kk], xacc);
          xacc = MFMA(xh, wxl[kk], xacc);
        }
      }
    }
  } else {
    short8 whh[16], whl[16], wih[16], wil[16];
    #pragma unroll
    for (int kk = 0; kk < 16; kk++) cvt8(Whh1 + (size_t)gcol*nH + kk*32 + ke, whh[kk], whl[kk]);
    #pragma unroll
    for (int kk = 0; kk < 16; kk++) cvt8(Wih1 + (size_t)gcol*nH + kk*32 + ke, wih[kk], wil[kk]);

    for (int t = 0; t < nT; t++){
      f32x4 acc = {0.f,0.f,0.f,0.f};
      poll(fb, NEG, t-1, dead);                    // own-layer peers at t-1
      const short* h2b = h2r + (size_t)((t+3)&3)*SLOT_ELEMS + brow*1024;
      #pragma unroll
      for (int kk = 0; kk < 16; kk++){
        short8 hh = aload16(h2b + kk*32 + ke);
        short8 hl = aload16(h2b + 512 + kk*32 + ke);
        acc = MFMA(hh, whh[kk], acc);
        acc = MFMA(hl, whh[kk], acc);
        acc = MFMA(hh, whl[kk], acc);
      }
      poll(fb, t, NEG, dead);                      // layer-0 produced h1[t]
      const short* h1b = h1r + (size_t)(t&7)*SLOT_ELEMS + brow*1024;
      #pragma unroll
      for (int kk = 0; kk < 16; kk++){
        short8 hh = aload16(h1b + kk*32 + ke);
        short8 hl = aload16(h1b + 512 + kk*32 + ke);
        acc = MFMA(hh, wih[kk], acc);
        acc = MFMA(hl, wih[kk], acc);
        acc = MFMA(hh, wil[kk], acc);
      }
      CELL(acc, h2r + (size_t)(t&3)*SLOT_ELEMS + (bs<<4)*1024, t, (t == nT-1));
    }

    // final FC in fp32 VALU: out = h2last @ fc_w^T + fc_b (blocks ns<16)
    if (ns < 16){
      poll(fb, NEG, nT-1, dead);
      const int orow = (bs<<4) + bl;
      const int ocol = (ns<<4) + jj;
      const unsigned long long* hq = (const unsigned long long*)(h2last + (size_t)orow*nH);
      const float* wr = fcw + (size_t)ocol*nH;
      float s0=0.f, s1=0.f, s2=0.f, s3=0.f;
      #pragma unroll 8
      for (int k = 0; k < nH; k += 8){
        union{ unsigned long long u; float f[2]; } q0,q1,q2,q3;
        q0.u = __hip_atomic_load(hq + (k>>1)    , __ATOMIC_RELAXED, SCOPE_AGENT);
        q1.u = __hip_atomic_load(hq + (k>>1) + 1, __ATOMIC_RELAXED, SCOPE_AGENT);
        q2.u = __hip_atomic_load(hq + (k>>1) + 2, __ATOMIC_RELAXED, SCOPE_AGENT);
        q3.u = __hip_atomic_load(hq + (k>>1) + 3, __ATOMIC_RELAXED, SCOPE_AGENT);
        fvec4 w0 = *(const fvec4*)(wr + k);
        fvec4 w1 = *(const fvec4*)(wr + k + 4);
        s0 += q0.f[0]*w0[0] + q0.f[1]*w0[1];
        s1 += q1.f[0]*w0[2] + q1.f[1]*w0[3];
        s2 += q2.f[0]*w1[0] + q2.f[1]*w1[1];
        s3 += q3.f[0]*w1[2] + q3.f[1]*w1[3];
      }
      out[(size_t)orow*nO + ocol] = s0 + s1 + s2 + s3 + fcb[ocol];
    }
  }
  #undef CELL
}

extern "C" void kernel_launch(void* const* d_in, const int* in_sizes, int n_in,
                              void* d_out, int out_size, void* d_ws, size_t ws_size,
                              hipStream_t stream)
{
  char* ws = (char*)d_ws;
  int*   flags  = (int*)ws;
  short* h1r    = (short*)(ws + RING_OFF);                 // 8 slots
  short* h2r    = h1r + 8ull * SLOT_ELEMS;                 // 4 slots
  float* h2last = (float*)((char*)(h2r + 4ull * SLOT_ELEMS));

  hipMemsetAsync(ws, 0xFF, 4*64*sizeof(int), stream);            // flags = -1
  hipMemsetAsync(h1r + 7ull*SLOT_ELEMS, 0, SLOT_BYTES, stream);  // h1[-1] = 0 (slot 7)
  hipMemsetAsync(h2r + 3ull*SLOT_ELEMS, 0, SLOT_BYTES, stream);  // h2[-1] = 0 (slot 3)

  const float* x    = (const float*)d_in[0];
  const float* Wih0 = (const float*)d_in[1];
  const float* Whh0 = (const float*)d_in[2];
  const float* bih0 = (const float*)d_in[3];
  const float* bhh0 = (const float*)d_in[4];
  const float* Wih1 = (const float*)d_in[5];
  const float* Whh1 = (const float*)d_in[6];
  const float* bih1 = (const float*)d_in[7];
  const float* bhh1 = (const float*)d_in[8];
  const float* fcw  = (const float*)d_in[9];
  const float* fcb  = (const float*)d_in[10];
  float* out = (float*)d_out;

  lstm_kernel<<<256, 256, 0, stream>>>(x, Wih0, Whh0, bih0, bhh0,
      Wih1, Whh1, bih1, bhh1, fcw, fcb, out, h1r, h2r, h2last, flags);
}

// Round 3
// 22841.341 us; speedup vs baseline: 1.6269x; 1.6269x over previous
//
#include <hip/hip_runtime.h>
#include <hip/hip_bf16.h>
#include <stdint.h>

typedef short short8 __attribute__((ext_vector_type(8)));
typedef float f32x4  __attribute__((ext_vector_type(4)));
typedef float fvec4  __attribute__((ext_vector_type(4)));

#define SCOPE_AGENT __HIP_MEMORY_SCOPE_AGENT
#define MFMA(a,b,c) __builtin_amdgcn_mfma_f32_16x16x32_bf16((a),(b),(c),0,0,0)

constexpr int nB = 64, nT = 1024, nD = 256, nH = 512, nO = 256;
constexpr int SLOT_ELEMS = 64 * 1024;                 // 64 rows x (512 hi | 512 lo) bf16
constexpr size_t SLOT_BYTES = (size_t)SLOT_ELEMS * 2; // 128 KiB
constexpr size_t RING_OFF = 4096;
constexpr int NEG = -0x40000000;

__device__ __forceinline__ float sigm(float x){ return 1.f/(1.f + __expf(-x)); }

// fp32 -> (hi, lo) bf16 pair, 8 contiguous elements
__device__ __forceinline__ void cvt8(const float* p, short8& hi, short8& lo){
  fvec4 a = *(const fvec4*)p;
  fvec4 b = *(const fvec4*)(p + 4);
  #pragma unroll
  for (int j = 0; j < 8; j++){
    float v = (j < 4) ? a[j] : b[j-4];
    __hip_bfloat16 h = __float2bfloat16(v);
    float r = v - __bfloat162float(h);
    hi[j] = (short)__bfloat16_as_ushort(h);
    lo[j] = (short)__bfloat16_as_ushort(__float2bfloat16(r));
  }
}

__device__ __forceinline__ unsigned pack2(float a, float b){
  unsigned ha = __bfloat16_as_ushort(__float2bfloat16(a));
  unsigned hb = __bfloat16_as_ushort(__float2bfloat16(b));
  return ha | (hb << 16);
}
__device__ __forceinline__ unsigned pack2lo(float a, float b){
  float ra = a - __bfloat162float(__float2bfloat16(a));
  float rb = b - __bfloat162float(__float2bfloat16(b));
  return pack2(ra, rb);
}

// agent-scope (LLC-coherent) 16B load = two 8B atomic loads; required because
// ring slots are rewritten within a launch (plain loads could hit stale L1/L2).
__device__ __forceinline__ short8 aload16(const short* p){
  union { unsigned long long u[2]; short8 v; } r;
  const unsigned long long* q = (const unsigned long long*)p;
  r.u[0] = __hip_atomic_load(q,     __ATOMIC_RELAXED, SCOPE_AGENT);
  r.u[1] = __hip_atomic_load(q + 1, __ATOMIC_RELAXED, SCOPE_AGENT);
  return r.v;
}

// Wave 0 polls 64 flags (lanes 0..31: layer-0, lanes 32..63: layer-1) with
// s_sleep backoff; waves 1-3 park at the barrier (no memory traffic).
// Unthrottled 1024-wave spinning saturated the flag LLC lines (R2: 36us/step).
__device__ __forceinline__ void poll(const int* fb, int t0, int t1){
  if (threadIdx.x < 64){
    int lid = threadIdx.x;
    int tgt = (lid < 32) ? t0 : t1;
    const int* p = fb + lid;
    int spins = 0;
    for(;;){
      int v = __hip_atomic_load(p, __ATOMIC_RELAXED, SCOPE_AGENT);
      if (__all(v >= tgt)) break;
      if (++spins > (1<<15)) break;               // fail-safe, never hang
      if (spins > 8) __builtin_amdgcn_s_sleep(2); // ~128-cycle backoff
    }
    __builtin_amdgcn_fence(__ATOMIC_ACQUIRE, "agent");
  }
  __syncthreads();
}

__global__ __launch_bounds__(256, 1) void lstm_kernel(
    const float* __restrict__ x,
    const float* __restrict__ Wih0, const float* __restrict__ Whh0,
    const float* __restrict__ bih0, const float* __restrict__ bhh0,
    const float* __restrict__ Wih1, const float* __restrict__ Whh1,
    const float* __restrict__ bih1, const float* __restrict__ bhh1,
    const float* __restrict__ fcw, const float* __restrict__ fcb,
    float* __restrict__ out,
    short* __restrict__ h1r, short* __restrict__ h2r,
    float* __restrict__ h2last, int* __restrict__ flags)
{
  const int bid   = blockIdx.x;
  const int layer = bid & 1;
  const int bs    = (bid >> 1) & 3;   // batch slice (16 rows)
  const int ns    = bid >> 3;         // H-chunk (16 cols)
  const int tid   = threadIdx.x;
  const int w     = tid >> 6;         // wave = gate (i,f,g,o)
  const int l     = tid & 63;
  const int lm    = l & 15;
  const int ke    = (l >> 4) << 3;    // k offset within K=32 step

  int* fb     = flags + (bs << 6);
  int* myflag = fb + (layer << 5) + ns;

  __shared__ float glds[4][16][16];

  const int gcol = (w << 9) + (ns << 4) + lm;   // gate row in [0,2048)
  const int brow = (bs << 4) + lm;              // batch row (A fragment)
  const int bl   = tid >> 4, jj = tid & 15;     // per-thread cell (row, col)
  const int hcolbase = ns << 4;

  float c_reg = 0.f;
  float bias  = layer == 0 ? bih0[gcol] + bhh0[gcol] : bih1[gcol] + bhh1[gcol];

  // ---- cell update macro (gates -> c,h -> hi/lo bf16 ring store -> flag) ----
  #define CELL(ACC, SLOTBASE, T, LAST)                                          \
  {                                                                             \
    _Pragma("unroll")                                                           \
    for (int r = 0; r < 4; r++) glds[w][((l>>4)<<2)+r][lm] = (ACC)[r] + bias;   \
    __syncthreads();                                                            \
    float gi = glds[0][bl][jj], gf = glds[1][bl][jj];                           \
    float gg = glds[2][bl][jj], go = glds[3][bl][jj];                           \
    float cn = sigm(gf)*c_reg + sigm(gi)*tanhf(gg);                             \
    c_reg = cn;                                                                 \
    float hn  = sigm(go)*tanhf(cn);                                             \
    float hn2 = __shfl_down(hn, 1);                                             \
    if (!(jj & 1)){                                                             \
      short* p = (SLOTBASE) + bl*1024 + hcolbase + jj;                          \
      __hip_atomic_store((unsigned*)p,       pack2(hn,hn2),   __ATOMIC_RELAXED, SCOPE_AGENT); \
      __hip_atomic_store((unsigned*)(p+512), pack2lo(hn,hn2), __ATOMIC_RELAXED, SCOPE_AGENT); \
    }                                                                           \
    if (LAST)                                                                   \
      __hip_atomic_store(h2last + (size_t)((bs<<4)+bl)*nH + hcolbase + jj, hn,  \
                         __ATOMIC_RELAXED, SCOPE_AGENT);                        \
    __syncthreads();  /* vmcnt(0) drain of all waves' stores */                 \
    if (tid == 0) __hip_atomic_store(myflag, (T), __ATOMIC_RELEASE, SCOPE_AGENT); \
  }

  if (layer == 0){
    short8 wxh[8], wxl[8], whh[16], whl[16];      // hi/lo weight frags in VGPRs
    #pragma unroll
    for (int kk = 0; kk < 8;  kk++) cvt8(Wih0 + (size_t)gcol*nD + kk*32 + ke, wxh[kk], wxl[kk]);
    #pragma unroll
    for (int kk = 0; kk < 16; kk++) cvt8(Whh0 + (size_t)gcol*nH + kk*32 + ke, whh[kk], whl[kk]);

    // prologue: x-projection for t=0
    f32x4 xacc = {0.f,0.f,0.f,0.f};
    {
      const float* xb = x + ((size_t)brow*nT + 0)*nD + ke;
      #pragma unroll
      for (int kk = 0; kk < 8; kk++){
        short8 xh, xl; cvt8(xb + kk*32, xh, xl);
        xacc = MFMA(xh, wxh[kk], xacc);
        xacc = MFMA(xl, wxh[kk], xacc);
        xacc = MFMA(xh, wxl[kk], xacc);
      }
    }

    for (int t = 0; t < nT; t++){
      poll(fb, t-1, t-8);                          // L0 peers t-1; L1 ring backpressure
      f32x4 acc = xacc;
      const short* hb = h1r + (size_t)((t+7)&7)*SLOT_ELEMS + brow*1024;
      #pragma unroll
      for (int kk = 0; kk < 16; kk++){
        short8 hh = aload16(hb + kk*32 + ke);
        short8 hl = aload16(hb + 512 + kk*32 + ke);
        acc = MFMA(hh, whh[kk], acc);
        acc = MFMA(hl, whh[kk], acc);
        acc = MFMA(hh, whl[kk], acc);
      }
      CELL(acc, h1r + (size_t)(t&7)*SLOT_ELEMS + (bs<<4)*1024, t, 0);
      if (t + 1 < nT){                             // x-proj for t+1 off critical path
        xacc = (f32x4){0.f,0.f,0.f,0.f};
        const float* xb = x + ((size_t)brow*nT + (t+1))*nD + ke;
        #pragma unroll
        for (int kk = 0; kk < 8; kk++){
          short8 xh, xl; cvt8(xb + kk*32, xh, xl);
          xacc = MFMA(xh, wxh[kk], xacc);
          xacc = MFMA(xl, wxh[kk], xacc);
          xacc = MFMA(xh, wxl[kk], xacc);
        }
      }
    }
  } else {
    short8 whh[16], whl[16], wih[16], wil[16];
    #pragma unroll
    for (int kk = 0; kk < 16; kk++) cvt8(Whh1 + (size_t)gcol*nH + kk*32 + ke, whh[kk], whl[kk]);
    #pragma unroll
    for (int kk = 0; kk < 16; kk++) cvt8(Wih1 + (size_t)gcol*nH + kk*32 + ke, wih[kk], wil[kk]);

    for (int t = 0; t < nT; t++){
      f32x4 acc = {0.f,0.f,0.f,0.f};
      poll(fb, NEG, t-1);                          // own-layer peers at t-1
      const short* h2b = h2r + (size_t)((t+3)&3)*SLOT_ELEMS + brow*1024;
      #pragma unroll
      for (int kk = 0; kk < 16; kk++){
        short8 hh = aload16(h2b + kk*32 + ke);
        short8 hl = aload16(h2b + 512 + kk*32 + ke);
        acc = MFMA(hh, whh[kk], acc);
        acc = MFMA(hl, whh[kk], acc);
        acc = MFMA(hh, whl[kk], acc);
      }
      poll(fb, t, NEG);                            // layer-0 produced h1[t]
      const short* h1b = h1r + (size_t)(t&7)*SLOT_ELEMS + brow*1024;
      #pragma unroll
      for (int kk = 0; kk < 16; kk++){
        short8 hh = aload16(h1b + kk*32 + ke);
        short8 hl = aload16(h1b + 512 + kk*32 + ke);
        acc = MFMA(hh, wih[kk], acc);
        acc = MFMA(hl, wih[kk], acc);
        acc = MFMA(hh, wil[kk], acc);
      }
      CELL(acc, h2r + (size_t)(t&3)*SLOT_ELEMS + (bs<<4)*1024, t, (t == nT-1));
    }

    // final FC in fp32 VALU: out = h2last @ fc_w^T + fc_b (blocks ns<16)
    if (ns < 16){
      poll(fb, NEG, nT-1);
      const int orow = (bs<<4) + bl;
      const int ocol = (ns<<4) + jj;
      const unsigned long long* hq = (const unsigned long long*)(h2last + (size_t)orow*nH);
      const float* wr = fcw + (size_t)ocol*nH;
      float s0=0.f, s1=0.f, s2=0.f, s3=0.f;
      #pragma unroll 8
      for (int k = 0; k < nH; k += 8){
        union{ unsigned long long u; float f[2]; } q0,q1,q2,q3;
        q0.u = __hip_atomic_load(hq + (k>>1)    , __ATOMIC_RELAXED, SCOPE_AGENT);
        q1.u = __hip_atomic_load(hq + (k>>1) + 1, __ATOMIC_RELAXED, SCOPE_AGENT);
        q2.u = __hip_atomic_load(hq + (k>>1) + 2, __ATOMIC_RELAXED, SCOPE_AGENT);
        q3.u = __hip_atomic_load(hq + (k>>1) + 3, __ATOMIC_RELAXED, SCOPE_AGENT);
        fvec4 w0 = *(const fvec4*)(wr + k);
        fvec4 w1 = *(const fvec4*)(wr + k + 4);
        s0 += q0.f[0]*w0[0] + q0.f[1]*w0[1];
        s1 += q1.f[0]*w0[2] + q1.f[1]*w0[3];
        s2 += q2.f[0]*w1[0] + q2.f[1]*w1[1];
        s3 += q3.f[0]*w1[2] + q3.f[1]*w1[3];
      }
      out[(size_t)orow*nO + ocol] = s0 + s1 + s2 + s3 + fcb[ocol];
    }
  }
  #undef CELL
}

extern "C" void kernel_launch(void* const* d_in, const int* in_sizes, int n_in,
                              void* d_out, int out_size, void* d_ws, size_t ws_size,
                              hipStream_t stream)
{
  char* ws = (char*)d_ws;
  int*   flags  = (int*)ws;
  short* h1r    = (short*)(ws + RING_OFF);                 // 8 slots
  short* h2r    = h1r + 8ull * SLOT_ELEMS;                 // 4 slots
  float* h2last = (float*)((char*)(h2r + 4ull * SLOT_ELEMS));

  hipMemsetAsync(ws, 0xFF, 4*64*sizeof(int), stream);            // flags = -1
  hipMemsetAsync(h1r + 7ull*SLOT_ELEMS, 0, SLOT_BYTES, stream);  // h1[-1] = 0 (slot 7)
  hipMemsetAsync(h2r + 3ull*SLOT_ELEMS, 0, SLOT_BYTES, stream);  // h2[-1] = 0 (slot 3)

  const float* x    = (const float*)d_in[0];
  const float* Wih0 = (const float*)d_in[1];
  const float* Whh0 = (const float*)d_in[2];
  const float* bih0 = (const float*)d_in[3];
  const float* bhh0 = (const float*)d_in[4];
  const float* Wih1 = (const float*)d_in[5];
  const float* Whh1 = (const float*)d_in[6];
  const float* bih1 = (const float*)d_in[7];
  const float* bhh1 = (const float*)d_in[8];
  const float* fcw  = (const float*)d_in[9];
  const float* fcb  = (const float*)d_in[10];
  float* out = (float*)d_out;

  lstm_kernel<<<256, 256, 0, stream>>>(x, Wih0, Whh0, bih0, bhh0,
      Wih1, Whh1, bih1, bhh1, fcw, fcb, out, h1r, h2r, h2last, flags);
}

// Round 4
// 20104.164 us; speedup vs baseline: 1.8484x; 1.1361x over previous
//
#include <hip/hip_runtime.h>
#include <hip/hip_bf16.h>
#include <stdint.h>

typedef short short8 __attribute__((ext_vector_type(8)));
typedef float f32x4  __attribute__((ext_vector_type(4)));
typedef float fvec4  __attribute__((ext_vector_type(4)));

#define SCOPE_AGENT __HIP_MEMORY_SCOPE_AGENT
#define MFMA(a,b,c) __builtin_amdgcn_mfma_f32_16x16x32_bf16((a),(b),(c),0,0,0)

constexpr int nB = 64, nT = 1024, nD = 256, nH = 512, nO = 256;
constexpr int SLOT_ELEMS = 64 * 1024;                 // 64 rows x (512 hi | 512 lo) bf16
constexpr size_t SLOT_BYTES = (size_t)SLOT_ELEMS * 2; // 128 KiB
constexpr size_t RING_OFF = 4096;
constexpr int NEG = -0x40000000;

// X-macro repetition: every per-k fragment is an individually NAMED variable.
// R3's short8 arrays were demoted to scratch (VGPR_Count=156 << the 256 regs
// the weights need) -> per-step scratch reloads dominated the recurrence.
#define R8(M)  M(0) M(1) M(2) M(3) M(4) M(5) M(6) M(7)
#define R16(M) R8(M) M(8) M(9) M(10) M(11) M(12) M(13) M(14) M(15)

__device__ __forceinline__ float sigm(float x){ return 1.f/(1.f + __expf(-x)); }

// fp32 -> (hi, lo) bf16 pair, 8 contiguous elements
__device__ __forceinline__ void cvt8(const float* p, short8& hi, short8& lo){
  fvec4 a = *(const fvec4*)p;
  fvec4 b = *(const fvec4*)(p + 4);
  #pragma unroll
  for (int j = 0; j < 8; j++){
    float v = (j < 4) ? a[j] : b[j-4];
    __hip_bfloat16 h = __float2bfloat16(v);
    float r = v - __bfloat162float(h);
    hi[j] = (short)__bfloat16_as_ushort(h);
    lo[j] = (short)__bfloat16_as_ushort(__float2bfloat16(r));
  }
}

__device__ __forceinline__ unsigned pack2(float a, float b){
  unsigned ha = __bfloat16_as_ushort(__float2bfloat16(a));
  unsigned hb = __bfloat16_as_ushort(__float2bfloat16(b));
  return ha | (hb << 16);
}
__device__ __forceinline__ unsigned pack2lo(float a, float b){
  float ra = a - __bfloat162float(__float2bfloat16(a));
  float rb = b - __bfloat162float(__float2bfloat16(b));
  return pack2(ra, rb);
}

// agent-scope (LLC-coherent) 16B load = two 8B atomic loads; ring slots are
// rewritten within a launch, so plain loads could hit stale L1/L2.
__device__ __forceinline__ short8 aload16(const short* p){
  union { unsigned long long u[2]; short8 v; } r;
  const unsigned long long* q = (const unsigned long long*)p;
  r.u[0] = __hip_atomic_load(q,     __ATOMIC_RELAXED, SCOPE_AGENT);
  r.u[1] = __hip_atomic_load(q + 1, __ATOMIC_RELAXED, SCOPE_AGENT);
  return r.v;
}

// Wave 0 polls 64 flags (lanes 0..31: layer-0, lanes 32..63: layer-1) with
// s_sleep backoff; waves 1-3 park at the barrier.
__device__ __forceinline__ void poll(const int* fb, int t0, int t1){
  if (threadIdx.x < 64){
    int lid = threadIdx.x;
    int tgt = (lid < 32) ? t0 : t1;
    const int* p = fb + lid;
    int spins = 0;
    for(;;){
      int v = __hip_atomic_load(p, __ATOMIC_RELAXED, SCOPE_AGENT);
      if (__all(v >= tgt)) break;
      if (++spins > (1<<16)) break;               // fail-safe, never hang
      if (spins > 8) __builtin_amdgcn_s_sleep(1); // ~64-cycle backoff
    }
    __builtin_amdgcn_fence(__ATOMIC_ACQUIRE, "agent");
  }
  __syncthreads();
}

__global__ __launch_bounds__(256, 1) void lstm_kernel(
    const float* __restrict__ x,
    const float* __restrict__ Wih0, const float* __restrict__ Whh0,
    const float* __restrict__ bih0, const float* __restrict__ bhh0,
    const float* __restrict__ Wih1, const float* __restrict__ Whh1,
    const float* __restrict__ bih1, const float* __restrict__ bhh1,
    const float* __restrict__ fcw, const float* __restrict__ fcb,
    float* __restrict__ out,
    short* __restrict__ h1r, short* __restrict__ h2r,
    float* __restrict__ h2last, int* __restrict__ flags)
{
  const int bid   = blockIdx.x;
  const int layer = bid & 1;
  const int bs    = (bid >> 1) & 3;   // batch slice (16 rows)
  const int ns    = bid >> 3;         // H-chunk (16 cols)
  const int tid   = threadIdx.x;
  const int w     = tid >> 6;         // wave = gate (i,f,g,o)
  const int l     = tid & 63;
  const int lm    = l & 15;
  const int ke    = (l >> 4) << 3;    // k offset within K=32 step

  int* fb     = flags + (bs << 6);
  int* myflag = fb + (layer << 5) + ns;

  __shared__ float glds[4][16][16];

  const int gcol = (w << 9) + (ns << 4) + lm;   // gate row in [0,2048)
  const int brow = (bs << 4) + lm;              // batch row (A fragment)
  const int bl   = tid >> 4, jj = tid & 15;     // per-thread cell (row, col)
  const int hcolbase = ns << 4;

  float c_reg = 0.f;
  float bias  = layer == 0 ? bih0[gcol] + bhh0[gcol] : bih1[gcol] + bhh1[gcol];

  // ---- cell update (gates -> c,h -> hi/lo bf16 ring store -> flag) ----
  #define CELL(ACC, SLOTBASE, T, LAST)                                          \
  {                                                                             \
    _Pragma("unroll")                                                           \
    for (int r = 0; r < 4; r++) glds[w][((l>>4)<<2)+r][lm] = (ACC)[r] + bias;   \
    __syncthreads();                                                            \
    float gi = glds[0][bl][jj], gf = glds[1][bl][jj];                           \
    float gg = glds[2][bl][jj], go = glds[3][bl][jj];                           \
    float cn = sigm(gf)*c_reg + sigm(gi)*tanhf(gg);                             \
    c_reg = cn;                                                                 \
    float hn  = sigm(go)*tanhf(cn);                                             \
    float hn2 = __shfl_down(hn, 1);                                             \
    if (!(jj & 1)){                                                             \
      short* p = (SLOTBASE) + bl*1024 + hcolbase + jj;                          \
      __hip_atomic_store((unsigned*)p,       pack2(hn,hn2),   __ATOMIC_RELAXED, SCOPE_AGENT); \
      __hip_atomic_store((unsigned*)(p+512), pack2lo(hn,hn2), __ATOMIC_RELAXED, SCOPE_AGENT); \
    }                                                                           \
    if (LAST)                                                                   \
      __hip_atomic_store(h2last + (size_t)((bs<<4)+bl)*nH + hcolbase + jj, hn,  \
                         __ATOMIC_RELAXED, SCOPE_AGENT);                        \
    __syncthreads();  /* vmcnt(0) drain of all waves' stores */                 \
    if (tid == 0) __hip_atomic_store(myflag, (T), __ATOMIC_RELEASE, SCOPE_AGENT); \
  }

  if (layer == 0){
    // ---- named weight fragments (24 hi + 24 lo = 192 VGPRs) ----
    #define DW0X(i) short8 wxh##i, wxl##i;
    R8(DW0X)
    #define DW0H(i) short8 whh##i, whl##i;
    R16(DW0H)
    #define LW0X(i) cvt8(Wih0 + (size_t)gcol*nD + i*32 + ke, wxh##i, wxl##i);
    R8(LW0X)
    #define LW0H(i) cvt8(Whh0 + (size_t)gcol*nH + i*32 + ke, whh##i, whl##i);
    R16(LW0H)

    // x-projection for t=0
    f32x4 xc0 = {0.f,0.f,0.f,0.f}, xc1 = {0.f,0.f,0.f,0.f};
    {
      const float* xb = x + ((size_t)brow*nT + 0)*nD + ke;
      #define XP0(i) { short8 th, tl; cvt8(xb + i*32, th, tl);                  \
        f32x4& d = (i%2) ? xc1 : xc0;                                           \
        d = MFMA(th, wxh##i, d); d = MFMA(tl, wxh##i, d); d = MFMA(th, wxl##i, d); }
      R8(XP0)
    }

    for (int t = 0; t < nT; t++){
      poll(fb, t-1, t-8);                       // L0 peers t-1; L1 ring backpressure
      const short* hb = h1r + (size_t)((t+7)&7)*SLOT_ELEMS + brow*1024;
      // issue all 32 h loads (128 VGPRs in flight)
      #define HL0(i) short8 vhh##i = aload16(hb + i*32 + ke);                   \
                     short8 vhl##i = aload16(hb + 512 + i*32 + ke);
      R16(HL0)
      // x-projection for t+1 overlaps the LLC latency of the h loads
      f32x4 xn0 = {0.f,0.f,0.f,0.f}, xn1 = {0.f,0.f,0.f,0.f};
      if (t + 1 < nT){
        const float* xb = x + ((size_t)brow*nT + (t+1))*nD + ke;
        #define XPN(i) { short8 th, tl; cvt8(xb + i*32, th, tl);                \
          f32x4& d = (i%2) ? xn1 : xn0;                                         \
          d = MFMA(th, wxh##i, d); d = MFMA(tl, wxh##i, d); d = MFMA(th, wxl##i, d); }
        R8(XPN)
      }
      // h MFMAs, 4 parallel accumulator chains
      f32x4 ac0 = xc0, ac1 = xc1, ac2 = {0.f,0.f,0.f,0.f}, ac3 = {0.f,0.f,0.f,0.f};
      #define HM0(i) { f32x4& d = (i%4==0)?ac0:((i%4==1)?ac1:((i%4==2)?ac2:ac3)); \
        d = MFMA(vhh##i, whh##i, d); d = MFMA(vhl##i, whh##i, d); d = MFMA(vhh##i, whl##i, d); }
      R16(HM0)
      f32x4 acc = ac0 + ac1 + ac2 + ac3;
      CELL(acc, h1r + (size_t)(t&7)*SLOT_ELEMS + (bs<<4)*1024, t, 0);
      xc0 = xn0; xc1 = xn1;
    }
  } else {
    // ---- named weight fragments (32 hi + 32 lo = 256 VGPRs) ----
    #define DW1A(i) short8 ahh##i, ahl##i;     // Whh1
    R16(DW1A)
    #define DW1B(i) short8 bhh##i, bhl##i;     // Wih1
    R16(DW1B)
    #define LW1A(i) cvt8(Whh1 + (size_t)gcol*nH + i*32 + ke, ahh##i, ahl##i);
    R16(LW1A)
    #define LW1B(i) cvt8(Wih1 + (size_t)gcol*nH + i*32 + ke, bhh##i, bhl##i);
    R16(LW1B)

    for (int t = 0; t < nT; t++){
      poll(fb, t, t-1);                         // merged: L0>=t AND own peers>=t-1
      // h2[t-1] part
      const short* h2b = h2r + (size_t)((t+3)&3)*SLOT_ELEMS + brow*1024;
      #define HL2(i) short8 u2h##i = aload16(h2b + i*32 + ke);                  \
                     short8 u2l##i = aload16(h2b + 512 + i*32 + ke);
      R16(HL2)
      f32x4 ac0 = {0.f,0.f,0.f,0.f}, ac1 = {0.f,0.f,0.f,0.f};
      f32x4 ac2 = {0.f,0.f,0.f,0.f}, ac3 = {0.f,0.f,0.f,0.f};
      #define HM2(i) { f32x4& d = (i%4==0)?ac0:((i%4==1)?ac1:((i%4==2)?ac2:ac3)); \
        d = MFMA(u2h##i, ahh##i, d); d = MFMA(u2l##i, ahh##i, d); d = MFMA(u2h##i, ahl##i, d); }
      R16(HM2)
      // h1[t] part
      const short* h1b = h1r + (size_t)(t&7)*SLOT_ELEMS + brow*1024;
      #define HL1(i) short8 u1h##i = aload16(h1b + i*32 + ke);                  \
                     short8 u1l##i = aload16(h1b + 512 + i*32 + ke);
      R16(HL1)
      #define HM1(i) { f32x4& d = (i%4==0)?ac0:((i%4==1)?ac1:((i%4==2)?ac2:ac3)); \
        d = MFMA(u1h##i, bhh##i, d); d = MFMA(u1l##i, bhh##i, d); d = MFMA(u1h##i, bhl##i, d); }
      R16(HM1)
      f32x4 acc = ac0 + ac1 + ac2 + ac3;
      CELL(acc, h2r + (size_t)(t&3)*SLOT_ELEMS + (bs<<4)*1024, t, (t == nT-1));
    }

    // final FC in fp32 VALU: out = h2last @ fc_w^T + fc_b (blocks ns<16)
    if (ns < 16){
      poll(fb, NEG, nT-1);
      const int orow = (bs<<4) + bl;
      const int ocol = (ns<<4) + jj;
      const unsigned long long* hq = (const unsigned long long*)(h2last + (size_t)orow*nH);
      const float* wr = fcw + (size_t)ocol*nH;
      float s0=0.f, s1=0.f, s2=0.f, s3=0.f;
      #pragma unroll 8
      for (int k = 0; k < nH; k += 8){
        union{ unsigned long long u; float f[2]; } q0,q1,q2,q3;
        q0.u = __hip_atomic_load(hq + (k>>1)    , __ATOMIC_RELAXED, SCOPE_AGENT);
        q1.u = __hip_atomic_load(hq + (k>>1) + 1, __ATOMIC_RELAXED, SCOPE_AGENT);
        q2.u = __hip_atomic_load(hq + (k>>1) + 2, __ATOMIC_RELAXED, SCOPE_AGENT);
        q3.u = __hip_atomic_load(hq + (k>>1) + 3, __ATOMIC_RELAXED, SCOPE_AGENT);
        fvec4 w0 = *(const fvec4*)(wr + k);
        fvec4 w1 = *(const fvec4*)(wr + k + 4);
        s0 += q0.f[0]*w0[0] + q0.f[1]*w0[1];
        s1 += q1.f[0]*w0[2] + q1.f[1]*w0[3];
        s2 += q2.f[0]*w1[0] + q2.f[1]*w1[1];
        s3 += q3.f[0]*w1[2] + q3.f[1]*w1[3];
      }
      out[(size_t)orow*nO + ocol] = s0 + s1 + s2 + s3 + fcb[ocol];
    }
  }
  #undef CELL
}

extern "C" void kernel_launch(void* const* d_in, const int* in_sizes, int n_in,
                              void* d_out, int out_size, void* d_ws, size_t ws_size,
                              hipStream_t stream)
{
  char* ws = (char*)d_ws;
  int*   flags  = (int*)ws;
  short* h1r    = (short*)(ws + RING_OFF);                 // 8 slots
  short* h2r    = h1r + 8ull * SLOT_ELEMS;                 // 4 slots
  float* h2last = (float*)((char*)(h2r + 4ull * SLOT_ELEMS));

  hipMemsetAsync(ws, 0xFF, 4*64*sizeof(int), stream);            // flags = -1
  hipMemsetAsync(h1r + 7ull*SLOT_ELEMS, 0, SLOT_BYTES, stream);  // h1[-1] = 0 (slot 7)
  hipMemsetAsync(h2r + 3ull*SLOT_ELEMS, 0, SLOT_BYTES, stream);  // h2[-1] = 0 (slot 3)

  const float* x    = (const float*)d_in[0];
  const float* Wih0 = (const float*)d_in[1];
  const float* Whh0 = (const float*)d_in[2];
  const float* bih0 = (const float*)d_in[3];
  const float* bhh0 = (const float*)d_in[4];
  const float* Wih1 = (const float*)d_in[5];
  const float* Whh1 = (const float*)d_in[6];
  const float* bih1 = (const float*)d_in[7];
  const float* bhh1 = (const float*)d_in[8];
  const float* fcw  = (const float*)d_in[9];
  const float* fcb  = (const float*)d_in[10];
  float* out = (float*)d_out;

  lstm_kernel<<<256, 256, 0, stream>>>(x, Wih0, Whh0, bih0, bhh0,
      Wih1, Whh1, bih1, bhh1, fcw, fcb, out, h1r, h2r, h2last, flags);
}

// Round 5
// 20086.450 us; speedup vs baseline: 1.8501x; 1.0009x over previous
//
#include <hip/hip_runtime.h>
#include <hip/hip_bf16.h>
#include <stdint.h>

typedef short short8 __attribute__((ext_vector_type(8)));
typedef float f32x4  __attribute__((ext_vector_type(4)));
typedef float fvec4  __attribute__((ext_vector_type(4)));

#define SCOPE_AGENT __HIP_MEMORY_SCOPE_AGENT
#define MFMA(a,b,c) __builtin_amdgcn_mfma_f32_16x16x32_bf16((a),(b),(c),0,0,0)

constexpr int nB = 64, nT = 1024, nD = 256, nH = 512, nO = 256;
constexpr int SLOT_ELEMS = 64 * 1024;                 // 64 rows x (512 hi | 512 lo) bf16
constexpr size_t SLOT_BYTES = (size_t)SLOT_ELEMS * 2; // 128 KiB
constexpr size_t RING_OFF = 4096;
constexpr int NEG = -0x40000000;

// X-macro repetition: per-k fragments as individually NAMED variables.
#define R8(M)  M(0) M(1) M(2) M(3) M(4) M(5) M(6) M(7)
#define R16(M) R8(M) M(8) M(9) M(10) M(11) M(12) M(13) M(14) M(15)

__device__ __forceinline__ float sigm(float x){ return 1.f/(1.f + __expf(-x)); }

// fp32 -> (hi, lo) bf16 pair, 8 contiguous elements
__device__ __forceinline__ void cvt8(const float* p, short8& hi, short8& lo){
  fvec4 a = *(const fvec4*)p;
  fvec4 b = *(const fvec4*)(p + 4);
  #pragma unroll
  for (int j = 0; j < 8; j++){
    float v = (j < 4) ? a[j] : b[j-4];
    __hip_bfloat16 h = __float2bfloat16(v);
    float r = v - __bfloat162float(h);
    hi[j] = (short)__bfloat16_as_ushort(h);
    lo[j] = (short)__bfloat16_as_ushort(__float2bfloat16(r));
  }
}

__device__ __forceinline__ unsigned pack2(float a, float b){
  unsigned ha = __bfloat16_as_ushort(__float2bfloat16(a));
  unsigned hb = __bfloat16_as_ushort(__float2bfloat16(b));
  return ha | (hb << 16);
}
__device__ __forceinline__ unsigned pack2lo(float a, float b){
  float ra = a - __bfloat162float(__float2bfloat16(a));
  float rb = b - __bfloat162float(__float2bfloat16(b));
  return pack2(ra, rb);
}

// R4 post-mortem: per-lane 8B agent-atomic h loads (~6M uncoalesced LLC
// transactions/step, ~48 MB/step) were the ~17us/step serial term. Replaced
// with plain wide loads guarded by release/acquire agent fences:
//   producer: plain stores -> barrier(vmcnt0) -> fence(release) -> atomic flag
//   consumer: atomic flag poll -> fence(acquire) -> plain short8 loads
__device__ __forceinline__ short8 ldh(const short* p){ return *(const short8*)p; }

// Wave 0 polls 64 flags (lanes 0..31: layer-0, lanes 32..63: layer-1) with
// s_sleep backoff; waves 1-3 park at the barrier. Acquire fence (L1/L2 inv)
// before the barrier makes subsequent plain loads LLC-fresh for all waves.
__device__ __forceinline__ void poll(const int* fb, int t0, int t1){
  if (threadIdx.x < 64){
    int lid = threadIdx.x;
    int tgt = (lid < 32) ? t0 : t1;
    const int* p = fb + lid;
    int spins = 0;
    for(;;){
      int v = __hip_atomic_load(p, __ATOMIC_RELAXED, SCOPE_AGENT);
      if (__all(v >= tgt)) break;
      if (++spins > (1<<16)) break;               // fail-safe, never hang
      if (spins > 8) __builtin_amdgcn_s_sleep(1); // ~64-cycle backoff
    }
    __builtin_amdgcn_fence(__ATOMIC_ACQUIRE, "agent");
  }
  __syncthreads();
}

__global__ __launch_bounds__(256, 1) void lstm_kernel(
    const float* __restrict__ x,
    const float* __restrict__ Wih0, const float* __restrict__ Whh0,
    const float* __restrict__ bih0, const float* __restrict__ bhh0,
    const float* __restrict__ Wih1, const float* __restrict__ Whh1,
    const float* __restrict__ bih1, const float* __restrict__ bhh1,
    const float* __restrict__ fcw, const float* __restrict__ fcb,
    float* __restrict__ out,
    short* __restrict__ h1r, short* __restrict__ h2r,
    float* __restrict__ h2last, int* __restrict__ flags)
{
  const int bid   = blockIdx.x;
  const int layer = bid & 1;
  const int bs    = (bid >> 1) & 3;   // batch slice (16 rows)
  const int ns    = bid >> 3;         // H-chunk (16 cols)
  const int tid   = threadIdx.x;
  const int w     = tid >> 6;         // wave = gate (i,f,g,o)
  const int l     = tid & 63;
  const int lm    = l & 15;
  const int ke    = (l >> 4) << 3;    // k offset within K=32 step

  int* fb     = flags + (bs << 6);
  int* myflag = fb + (layer << 5) + ns;

  __shared__ float glds[4][16][16];

  const int gcol = (w << 9) + (ns << 4) + lm;   // gate row in [0,2048)
  const int brow = (bs << 4) + lm;              // batch row (A fragment)
  const int bl   = tid >> 4, jj = tid & 15;     // per-thread cell (row, col)
  const int hcolbase = ns << 4;

  float c_reg = 0.f;
  float bias  = layer == 0 ? bih0[gcol] + bhh0[gcol] : bih1[gcol] + bhh1[gcol];

  // ---- cell update (gates -> c,h -> hi/lo bf16 ring store -> fence -> flag) ----
  #define CELL(ACC, SLOTBASE, T, LAST)                                          \
  {                                                                             \
    _Pragma("unroll")                                                           \
    for (int r = 0; r < 4; r++) glds[w][((l>>4)<<2)+r][lm] = (ACC)[r] + bias;   \
    __syncthreads();                                                            \
    float gi = glds[0][bl][jj], gf = glds[1][bl][jj];                           \
    float gg = glds[2][bl][jj], go = glds[3][bl][jj];                           \
    float cn = sigm(gf)*c_reg + sigm(gi)*tanhf(gg);                             \
    c_reg = cn;                                                                 \
    float hn  = sigm(go)*tanhf(cn);                                             \
    float hn2 = __shfl_down(hn, 1);                                             \
    if (!(jj & 1)){                                                             \
      short* p = (SLOTBASE) + bl*1024 + hcolbase + jj;                          \
      *(unsigned*)p       = pack2(hn, hn2);                                     \
      *(unsigned*)(p+512) = pack2lo(hn, hn2);                                   \
    }                                                                           \
    if (LAST)                                                                   \
      h2last[(size_t)((bs<<4)+bl)*nH + hcolbase + jj] = hn;                     \
    __syncthreads();  /* vmcnt(0): all waves' stores are in L2 */               \
    if (tid == 0){                                                              \
      __builtin_amdgcn_fence(__ATOMIC_RELEASE, "agent");  /* L2 -> LLC */       \
      __hip_atomic_store(myflag, (T), __ATOMIC_RELEASE, SCOPE_AGENT);           \
    }                                                                           \
  }

  if (layer == 0){
    // ---- named weight fragments (24 hi + 24 lo) ----
    #define DW0X(i) short8 wxh##i, wxl##i;
    R8(DW0X)
    #define DW0H(i) short8 whh##i, whl##i;
    R16(DW0H)
    #define LW0X(i) cvt8(Wih0 + (size_t)gcol*nD + i*32 + ke, wxh##i, wxl##i);
    R8(LW0X)
    #define LW0H(i) cvt8(Whh0 + (size_t)gcol*nH + i*32 + ke, whh##i, whl##i);
    R16(LW0H)

    // x-projection for t=0
    f32x4 xc0 = {0.f,0.f,0.f,0.f}, xc1 = {0.f,0.f,0.f,0.f};
    {
      const float* xb = x + ((size_t)brow*nT + 0)*nD + ke;
      #define XP0(i) { short8 th, tl; cvt8(xb + i*32, th, tl);                  \
        f32x4& d = (i%2) ? xc1 : xc0;                                           \
        d = MFMA(th, wxh##i, d); d = MFMA(tl, wxh##i, d); d = MFMA(th, wxl##i, d); }
      R8(XP0)
    }

    for (int t = 0; t < nT; t++){
      poll(fb, t-1, t-8);                       // L0 peers t-1; L1 ring backpressure
      const short* hb = h1r + (size_t)((t+7)&7)*SLOT_ELEMS + brow*1024;
      // issue all 32 plain wide h loads
      #define HL0(i) short8 vhh##i = ldh(hb + i*32 + ke);                       \
                     short8 vhl##i = ldh(hb + 512 + i*32 + ke);
      R16(HL0)
      // x-projection for t+1 overlaps the LLC latency of the h loads
      f32x4 xn0 = {0.f,0.f,0.f,0.f}, xn1 = {0.f,0.f,0.f,0.f};
      if (t + 1 < nT){
        const float* xb = x + ((size_t)brow*nT + (t+1))*nD + ke;
        #define XPN(i) { short8 th, tl; cvt8(xb + i*32, th, tl);                \
          f32x4& d = (i%2) ? xn1 : xn0;                                         \
          d = MFMA(th, wxh##i, d); d = MFMA(tl, wxh##i, d); d = MFMA(th, wxl##i, d); }
        R8(XPN)
      }
      // h MFMAs, 4 parallel accumulator chains
      f32x4 ac0 = xc0, ac1 = xc1, ac2 = {0.f,0.f,0.f,0.f}, ac3 = {0.f,0.f,0.f,0.f};
      #define HM0(i) { f32x4& d = (i%4==0)?ac0:((i%4==1)?ac1:((i%4==2)?ac2:ac3)); \
        d = MFMA(vhh##i, whh##i, d); d = MFMA(vhl##i, whh##i, d); d = MFMA(vhh##i, whl##i, d); }
      R16(HM0)
      f32x4 acc = ac0 + ac1 + ac2 + ac3;
      CELL(acc, h1r + (size_t)(t&7)*SLOT_ELEMS + (bs<<4)*1024, t, 0);
      xc0 = xn0; xc1 = xn1;
    }
  } else {
    // ---- named weight fragments ----
    #define DW1A(i) short8 ahh##i, ahl##i;     // Whh1
    R16(DW1A)
    #define DW1B(i) short8 bhh##i, bhl##i;     // Wih1
    R16(DW1B)
    #define LW1A(i) cvt8(Whh1 + (size_t)gcol*nH + i*32 + ke, ahh##i, ahl##i);
    R16(LW1A)
    #define LW1B(i) cvt8(Wih1 + (size_t)gcol*nH + i*32 + ke, bhh##i, bhl##i);
    R16(LW1B)

    for (int t = 0; t < nT; t++){
      poll(fb, t, t-1);                         // merged: L0>=t AND own peers>=t-1
      // h2[t-1] part
      const short* h2b = h2r + (size_t)((t+3)&3)*SLOT_ELEMS + brow*1024;
      #define HL2(i) short8 u2h##i = ldh(h2b + i*32 + ke);                      \
                     short8 u2l##i = ldh(h2b + 512 + i*32 + ke);
      R16(HL2)
      f32x4 ac0 = {0.f,0.f,0.f,0.f}, ac1 = {0.f,0.f,0.f,0.f};
      f32x4 ac2 = {0.f,0.f,0.f,0.f}, ac3 = {0.f,0.f,0.f,0.f};
      #define HM2(i) { f32x4& d = (i%4==0)?ac0:((i%4==1)?ac1:((i%4==2)?ac2:ac3)); \
        d = MFMA(u2h##i, ahh##i, d); d = MFMA(u2l##i, ahh##i, d); d = MFMA(u2h##i, ahl##i, d); }
      R16(HM2)
      // h1[t] part
      const short* h1b = h1r + (size_t)(t&7)*SLOT_ELEMS + brow*1024;
      #define HL1(i) short8 u1h##i = ldh(h1b + i*32 + ke);                      \
                     short8 u1l##i = ldh(h1b + 512 + i*32 + ke);
      R16(HL1)
      #define HM1(i) { f32x4& d = (i%4==0)?ac0:((i%4==1)?ac1:((i%4==2)?ac2:ac3)); \
        d = MFMA(u1h##i, bhh##i, d); d = MFMA(u1l##i, bhh##i, d); d = MFMA(u1h##i, bhl##i, d); }
      R16(HM1)
      f32x4 acc = ac0 + ac1 + ac2 + ac3;
      CELL(acc, h2r + (size_t)(t&3)*SLOT_ELEMS + (bs<<4)*1024, t, (t == nT-1));
    }

    // final FC in fp32 VALU: out = h2last @ fc_w^T + fc_b (blocks ns<16)
    if (ns < 16){
      poll(fb, NEG, nT-1);                      // acquire fence covers plain loads
      const int orow = (bs<<4) + bl;
      const int ocol = (ns<<4) + jj;
      const float* hr = h2last + (size_t)orow*nH;
      const float* wr = fcw + (size_t)ocol*nH;
      float s0=0.f, s1=0.f, s2=0.f, s3=0.f;
      #pragma unroll 8
      for (int k = 0; k < nH; k += 8){
        fvec4 h0 = *(const fvec4*)(hr + k);
        fvec4 h1 = *(const fvec4*)(hr + k + 4);
        fvec4 w0 = *(const fvec4*)(wr + k);
        fvec4 w1 = *(const fvec4*)(wr + k + 4);
        s0 += h0[0]*w0[0] + h0[1]*w0[1];
        s1 += h0[2]*w0[2] + h0[3]*w0[3];
        s2 += h1[0]*w1[0] + h1[1]*w1[1];
        s3 += h1[2]*w1[2] + h1[3]*w1[3];
      }
      out[(size_t)orow*nO + ocol] = s0 + s1 + s2 + s3 + fcb[ocol];
    }
  }
  #undef CELL
}

extern "C" void kernel_launch(void* const* d_in, const int* in_sizes, int n_in,
                              void* d_out, int out_size, void* d_ws, size_t ws_size,
                              hipStream_t stream)
{
  char* ws = (char*)d_ws;
  int*   flags  = (int*)ws;
  short* h1r    = (short*)(ws + RING_OFF);                 // 8 slots
  short* h2r    = h1r + 8ull * SLOT_ELEMS;                 // 4 slots
  float* h2last = (float*)((char*)(h2r + 4ull * SLOT_ELEMS));

  hipMemsetAsync(ws, 0xFF, 4*64*sizeof(int), stream);            // flags = -1
  hipMemsetAsync(h1r + 7ull*SLOT_ELEMS, 0, SLOT_BYTES, stream);  // h1[-1] = 0 (slot 7)
  hipMemsetAsync(h2r + 3ull*SLOT_ELEMS, 0, SLOT_BYTES, stream);  // h2[-1] = 0 (slot 3)

  const float* x    = (const float*)d_in[0];
  const float* Wih0 = (const float*)d_in[1];
  const float* Whh0 = (const float*)d_in[2];
  const float* bih0 = (const float*)d_in[3];
  const float* bhh0 = (const float*)d_in[4];
  const float* Wih1 = (const float*)d_in[5];
  const float* Whh1 = (const float*)d_in[6];
  const float* bih1 = (const float*)d_in[7];
  const float* bhh1 = (const float*)d_in[8];
  const float* fcw  = (const float*)d_in[9];
  const float* fcb  = (const float*)d_in[10];
  float* out = (float*)d_out;

  lstm_kernel<<<256, 256, 0, stream>>>(x, Wih0, Whh0, bih0, bhh0,
      Wih1, Whh1, bih1, bhh1, fcw, fcb, out, h1r, h2r, h2last, flags);
}

// Round 6
// 16286.104 us; speedup vs baseline: 2.2818x; 1.2333x over previous
//
#include <hip/hip_runtime.h>
#include <hip/hip_bf16.h>
#include <stdint.h>

typedef short short8 __attribute__((ext_vector_type(8)));
typedef float f32x4  __attribute__((ext_vector_type(4)));
typedef float fvec4  __attribute__((ext_vector_type(4)));

#define SCOPE_AGENT __HIP_MEMORY_SCOPE_AGENT
#define MFMA(a,b,c) __builtin_amdgcn_mfma_f32_16x16x32_bf16((a),(b),(c),0,0,0)

constexpr int nB = 64, nT = 1024, nD = 256, nH = 512, nO = 256;
constexpr int SLOT_ELEMS = 64 * 1024;                 // 64 rows x (512 hi | 512 lo) bf16
constexpr size_t SLOT_BYTES = (size_t)SLOT_ELEMS * 2; // 128 KiB
constexpr size_t RING_OFF = 4096;
constexpr int NEG = -0x40000000;

// X-macro repetition: per-k fragments as individually NAMED variables.
#define R8(M)  M(0) M(1) M(2) M(3) M(4) M(5) M(6) M(7)
#define R16(M) R8(M) M(8) M(9) M(10) M(11) M(12) M(13) M(14) M(15)

__device__ __forceinline__ float sigm(float x){ return 1.f/(1.f + __expf(-x)); }

// fp32 -> (hi, lo) bf16 pair, 8 contiguous elements
__device__ __forceinline__ void cvt8(const float* p, short8& hi, short8& lo){
  fvec4 a = *(const fvec4*)p;
  fvec4 b = *(const fvec4*)(p + 4);
  #pragma unroll
  for (int j = 0; j < 8; j++){
    float v = (j < 4) ? a[j] : b[j-4];
    __hip_bfloat16 h = __float2bfloat16(v);
    float r = v - __bfloat162float(h);
    hi[j] = (short)__bfloat16_as_ushort(h);
    lo[j] = (short)__bfloat16_as_ushort(__float2bfloat16(r));
  }
}

__device__ __forceinline__ unsigned pack2(float a, float b){
  unsigned ha = __bfloat16_as_ushort(__float2bfloat16(a));
  unsigned hb = __bfloat16_as_ushort(__float2bfloat16(b));
  return ha | (hb << 16);
}
__device__ __forceinline__ unsigned pack2lo(float a, float b){
  float ra = a - __bfloat162float(__float2bfloat16(a));
  float rb = b - __bfloat162float(__float2bfloat16(b));
  return pack2(ra, rb);
}

// R5 post-mortem: agent-scope RELEASE/ACQUIRE fences emit buffer_wbl2 /
// buffer_inv (full-L2 writeback / L1+L2 invalidate) -- 32 blocks x 2 full-
// cache ops per XCD per STEP, serializing at the L2: the ~19.6us/step floor.
// This round: FENCE-FREE protocol. All communicated data moves via agent-
// scope RELAXED atomics (cache-bypass, LLC-coherent). Ordering: each wave's
// h-stores are vmcnt(0)-drained by the compiler-emitted wait before
// s_barrier; the RELAXED flag store issues after the barrier, so h-data
// reaches the LLC before the flag does. No wbl2, no inv, anywhere.
__device__ __forceinline__ short8 aload16(const short* p){
  union { unsigned long long u[2]; short8 v; } r;
  const unsigned long long* q = (const unsigned long long*)p;
  r.u[0] = __hip_atomic_load(q,     __ATOMIC_RELAXED, SCOPE_AGENT);
  r.u[1] = __hip_atomic_load(q + 1, __ATOMIC_RELAXED, SCOPE_AGENT);
  return r.v;
}

// Wave 0 polls 64 flags (lanes 0..31: layer-0, 32..63: layer-1); waves 1-3
// park at the barrier. Busy-spin first (the ~600cy flag-load RT is a natural
// throttle for 256 polling waves); s_sleep only after 64 misses.
__device__ __forceinline__ void poll(const int* fb, int t0, int t1){
  if (threadIdx.x < 64){
    int lid = threadIdx.x;
    int tgt = (lid < 32) ? t0 : t1;
    const int* p = fb + lid;
    int spins = 0;
    for(;;){
      int v = __hip_atomic_load(p, __ATOMIC_RELAXED, SCOPE_AGENT);
      if (__all(v >= tgt)) break;
      if (++spins > (1<<17)) break;                // fail-safe, never hang
      if (spins > 64) __builtin_amdgcn_s_sleep(1);
    }
  }
  __syncthreads();
}

__global__ __launch_bounds__(256, 1) void lstm_kernel(
    const float* __restrict__ x,
    const float* __restrict__ Wih0, const float* __restrict__ Whh0,
    const float* __restrict__ bih0, const float* __restrict__ bhh0,
    const float* __restrict__ Wih1, const float* __restrict__ Whh1,
    const float* __restrict__ bih1, const float* __restrict__ bhh1,
    const float* __restrict__ fcw, const float* __restrict__ fcb,
    float* __restrict__ out,
    short* __restrict__ h1r, short* __restrict__ h2r,
    float* __restrict__ h2last, int* __restrict__ flags)
{
  const int bid   = blockIdx.x;
  const int layer = bid & 1;
  const int bs    = (bid >> 1) & 3;   // batch slice (16 rows)
  const int ns    = bid >> 3;         // H-chunk (16 cols)
  const int tid   = threadIdx.x;
  const int w     = tid >> 6;         // wave = gate (i,f,g,o)
  const int l     = tid & 63;
  const int lm    = l & 15;
  const int ke    = (l >> 4) << 3;    // k offset within K=32 step

  int* fb     = flags + (bs << 6);
  int* myflag = fb + (layer << 5) + ns;

  __shared__ float glds[4][16][16];

  const int gcol = (w << 9) + (ns << 4) + lm;   // gate row in [0,2048)
  const int brow = (bs << 4) + lm;              // batch row (A fragment)
  const int bl   = tid >> 4, jj = tid & 15;     // per-thread cell (row, col)
  const int hcolbase = ns << 4;

  float c_reg = 0.f;
  float bias  = layer == 0 ? bih0[gcol] + bhh0[gcol] : bih1[gcol] + bhh1[gcol];

  // ---- cell update (gates -> c,h -> hi/lo bf16 atomic ring store -> flag) ----
  #define CELL(ACC, SLOTBASE, T, LAST)                                          \
  {                                                                             \
    _Pragma("unroll")                                                           \
    for (int r = 0; r < 4; r++) glds[w][((l>>4)<<2)+r][lm] = (ACC)[r] + bias;   \
    __syncthreads();                                                            \
    float gi = glds[0][bl][jj], gf = glds[1][bl][jj];                           \
    float gg = glds[2][bl][jj], go = glds[3][bl][jj];                           \
    float cn = sigm(gf)*c_reg + sigm(gi)*tanhf(gg);                             \
    c_reg = cn;                                                                 \
    float hn  = sigm(go)*tanhf(cn);                                             \
    float hn2 = __shfl_down(hn, 1);                                             \
    if (!(jj & 1)){                                                             \
      short* p = (SLOTBASE) + bl*1024 + hcolbase + jj;                          \
      __hip_atomic_store((unsigned*)p,       pack2(hn,hn2),   __ATOMIC_RELAXED, SCOPE_AGENT); \
      __hip_atomic_store((unsigned*)(p+512), pack2lo(hn,hn2), __ATOMIC_RELAXED, SCOPE_AGENT); \
    }                                                                           \
    if (LAST)                                                                   \
      __hip_atomic_store(h2last + (size_t)((bs<<4)+bl)*nH + hcolbase + jj, hn,  \
                         __ATOMIC_RELAXED, SCOPE_AGENT);                        \
    __syncthreads();  /* compiler drains vmcnt(0) before s_barrier */           \
    if (tid == 0)                                                               \
      __hip_atomic_store(myflag, (T), __ATOMIC_RELAXED, SCOPE_AGENT);           \
  }

  if (layer == 0){
    // ---- named weight fragments (24 hi + 24 lo) ----
    #define DW0X(i) short8 wxh##i, wxl##i;
    R8(DW0X)
    #define DW0H(i) short8 whh##i, whl##i;
    R16(DW0H)
    #define LW0X(i) cvt8(Wih0 + (size_t)gcol*nD + i*32 + ke, wxh##i, wxl##i);
    R8(LW0X)
    #define LW0H(i) cvt8(Whh0 + (size_t)gcol*nH + i*32 + ke, whh##i, whl##i);
    R16(LW0H)

    // x-projection for t=0
    f32x4 xc0 = {0.f,0.f,0.f,0.f}, xc1 = {0.f,0.f,0.f,0.f};
    {
      const float* xb = x + ((size_t)brow*nT + 0)*nD + ke;
      #define XP0(i) { short8 th, tl; cvt8(xb + i*32, th, tl);                  \
        f32x4& d = (i%2) ? xc1 : xc0;                                           \
        d = MFMA(th, wxh##i, d); d = MFMA(tl, wxh##i, d); d = MFMA(th, wxl##i, d); }
      R8(XP0)
    }

    for (int t = 0; t < nT; t++){
      poll(fb, t-1, t-8);                       // L0 peers t-1; L1 ring backpressure
      const short* hb = h1r + (size_t)((t+7)&7)*SLOT_ELEMS + brow*1024;
      // issue all 32 h loads (LLC-coherent atomics)
      #define HL0(i) short8 vhh##i = aload16(hb + i*32 + ke);                   \
                     short8 vhl##i = aload16(hb + 512 + i*32 + ke);
      R16(HL0)
      // x-projection for t+1 overlaps the LLC latency of the h loads
      f32x4 xn0 = {0.f,0.f,0.f,0.f}, xn1 = {0.f,0.f,0.f,0.f};
      if (t + 1 < nT){
        const float* xb = x + ((size_t)brow*nT + (t+1))*nD + ke;
        #define XPN(i) { short8 th, tl; cvt8(xb + i*32, th, tl);                \
          f32x4& d = (i%2) ? xn1 : xn0;                                         \
          d = MFMA(th, wxh##i, d); d = MFMA(tl, wxh##i, d); d = MFMA(th, wxl##i, d); }
        R8(XPN)
      }
      // h MFMAs, 4 parallel accumulator chains
      f32x4 ac0 = xc0, ac1 = xc1, ac2 = {0.f,0.f,0.f,0.f}, ac3 = {0.f,0.f,0.f,0.f};
      #define HM0(i) { f32x4& d = (i%4==0)?ac0:((i%4==1)?ac1:((i%4==2)?ac2:ac3)); \
        d = MFMA(vhh##i, whh##i, d); d = MFMA(vhl##i, whh##i, d); d = MFMA(vhh##i, whl##i, d); }
      R16(HM0)
      f32x4 acc = ac0 + ac1 + ac2 + ac3;
      CELL(acc, h1r + (size_t)(t&7)*SLOT_ELEMS + (bs<<4)*1024, t, 0);
      xc0 = xn0; xc1 = xn1;
    }
  } else {
    // ---- named weight fragments ----
    #define DW1A(i) short8 ahh##i, ahl##i;     // Whh1
    R16(DW1A)
    #define DW1B(i) short8 bhh##i, bhl##i;     // Wih1
    R16(DW1B)
    #define LW1A(i) cvt8(Whh1 + (size_t)gcol*nH + i*32 + ke, ahh##i, ahl##i);
    R16(LW1A)
    #define LW1B(i) cvt8(Wih1 + (size_t)gcol*nH + i*32 + ke, bhh##i, bhl##i);
    R16(LW1B)

    for (int t = 0; t < nT; t++){
      poll(fb, t, t-1);                         // merged: L0>=t AND own peers>=t-1
      // h2[t-1] part
      const short* h2b = h2r + (size_t)((t+3)&3)*SLOT_ELEMS + brow*1024;
      #define HL2(i) short8 u2h##i = aload16(h2b + i*32 + ke);                  \
                     short8 u2l##i = aload16(h2b + 512 + i*32 + ke);
      R16(HL2)
      f32x4 ac0 = {0.f,0.f,0.f,0.f}, ac1 = {0.f,0.f,0.f,0.f};
      f32x4 ac2 = {0.f,0.f,0.f,0.f}, ac3 = {0.f,0.f,0.f,0.f};
      #define HM2(i) { f32x4& d = (i%4==0)?ac0:((i%4==1)?ac1:((i%4==2)?ac2:ac3)); \
        d = MFMA(u2h##i, ahh##i, d); d = MFMA(u2l##i, ahh##i, d); d = MFMA(u2h##i, ahl##i, d); }
      R16(HM2)
      // h1[t] part
      const short* h1b = h1r + (size_t)(t&7)*SLOT_ELEMS + brow*1024;
      #define HL1(i) short8 u1h##i = aload16(h1b + i*32 + ke);                  \
                     short8 u1l##i = aload16(h1b + 512 + i*32 + ke);
      R16(HL1)
      #define HM1(i) { f32x4& d = (i%4==0)?ac0:((i%4==1)?ac1:((i%4==2)?ac2:ac3)); \
        d = MFMA(u1h##i, bhh##i, d); d = MFMA(u1l##i, bhh##i, d); d = MFMA(u1h##i, bhl##i, d); }
      R16(HM1)
      f32x4 acc = ac0 + ac1 + ac2 + ac3;
      CELL(acc, h2r + (size_t)(t&3)*SLOT_ELEMS + (bs<<4)*1024, t, (t == nT-1));
    }

    // final FC in fp32 VALU: out = h2last @ fc_w^T + fc_b (blocks ns<16)
    if (ns < 16){
      poll(fb, NEG, nT-1);
      const int orow = (bs<<4) + bl;
      const int ocol = (ns<<4) + jj;
      const unsigned long long* hq = (const unsigned long long*)(h2last + (size_t)orow*nH);
      const float* wr = fcw + (size_t)ocol*nH;
      float s0=0.f, s1=0.f, s2=0.f, s3=0.f;
      #pragma unroll 8
      for (int k = 0; k < nH; k += 8){
        union{ unsigned long long u; float f[2]; } q0,q1,q2,q3;
        q0.u = __hip_atomic_load(hq + (k>>1)    , __ATOMIC_RELAXED, SCOPE_AGENT);
        q1.u = __hip_atomic_load(hq + (k>>1) + 1, __ATOMIC_RELAXED, SCOPE_AGENT);
        q2.u = __hip_atomic_load(hq + (k>>1) + 2, __ATOMIC_RELAXED, SCOPE_AGENT);
        q3.u = __hip_atomic_load(hq + (k>>1) + 3, __ATOMIC_RELAXED, SCOPE_AGENT);
        fvec4 w0 = *(const fvec4*)(wr + k);
        fvec4 w1 = *(const fvec4*)(wr + k + 4);
        s0 += q0.f[0]*w0[0] + q0.f[1]*w0[1];
        s1 += q1.f[0]*w0[2] + q1.f[1]*w0[3];
        s2 += q2.f[0]*w1[0] + q2.f[1]*w1[1];
        s3 += q3.f[0]*w1[2] + q3.f[1]*w1[3];
      }
      out[(size_t)orow*nO + ocol] = s0 + s1 + s2 + s3 + fcb[ocol];
    }
  }
  #undef CELL
}

extern "C" void kernel_launch(void* const* d_in, const int* in_sizes, int n_in,
                              void* d_out, int out_size, void* d_ws, size_t ws_size,
                              hipStream_t stream)
{
  char* ws = (char*)d_ws;
  int*   flags  = (int*)ws;
  short* h1r    = (short*)(ws + RING_OFF);                 // 8 slots
  short* h2r    = h1r + 8ull * SLOT_ELEMS;                 // 4 slots
  float* h2last = (float*)((char*)(h2r + 4ull * SLOT_ELEMS));

  hipMemsetAsync(ws, 0xFF, 4*64*sizeof(int), stream);            // flags = -1
  hipMemsetAsync(h1r + 7ull*SLOT_ELEMS, 0, SLOT_BYTES, stream);  // h1[-1] = 0 (slot 7)
  hipMemsetAsync(h2r + 3ull*SLOT_ELEMS, 0, SLOT_BYTES, stream);  // h2[-1] = 0 (slot 3)

  const float* x    = (const float*)d_in[0];
  const float* Wih0 = (const float*)d_in[1];
  const float* Whh0 = (const float*)d_in[2];
  const float* bih0 = (const float*)d_in[3];
  const float* bhh0 = (const float*)d_in[4];
  const float* Wih1 = (const float*)d_in[5];
  const float* Whh1 = (const float*)d_in[6];
  const float* bih1 = (const float*)d_in[7];
  const float* bhh1 = (const float*)d_in[8];
  const float* fcw  = (const float*)d_in[9];
  const float* fcb  = (const float*)d_in[10];
  float* out = (float*)d_out;

  lstm_kernel<<<256, 256, 0, stream>>>(x, Wih0, Whh0, bih0, bhh0,
      Wih1, Whh1, bih1, bhh1, fcw, fcb, out, h1r, h2r, h2last, flags);
}

// Round 7
// 5565.743 us; speedup vs baseline: 6.6767x; 2.9261x over previous
//
#include <hip/hip_runtime.h>
#include <hip/hip_bf16.h>
#include <stdint.h>

typedef short short8 __attribute__((ext_vector_type(8)));
typedef float f32x4  __attribute__((ext_vector_type(4)));
typedef float fvec4  __attribute__((ext_vector_type(4)));

#define SCOPE_AGENT __HIP_MEMORY_SCOPE_AGENT
#define MFMA(a,b,c) __builtin_amdgcn_mfma_f32_16x16x32_bf16((a),(b),(c),0,0,0)

constexpr int nB = 64, nT = 1024, nD = 256, nH = 512, nO = 256;
constexpr int SLOT_ELEMS = 64 * 1024;                 // 64 rows x (512 hi | 512 lo) bf16
constexpr size_t SLOT_BYTES = (size_t)SLOT_ELEMS * 2; // 128 KiB
constexpr size_t RING_OFF = 4096;
constexpr int NEG = -0x40000000;

// R6 post-mortem: per-step LLC transaction count was the wall (~6.3M 8B
// requests/step ~= LLC slot-rate ceiling). This round: waves K-SPLIT (each
// wave loads only its K-quarter of h, computes ALL 4 gates, partials reduced
// in LDS) -> 4x fewer h transactions, same MFMA count and same weight-register
// footprint per wave.
#define K4(M)  M(0) M(1) M(2) M(3)
#define GK2(M) M(0,0) M(1,0) M(2,0) M(3,0) M(0,1) M(1,1) M(2,1) M(3,1)
#define GK4(M) GK2(M) M(0,2) M(1,2) M(2,2) M(3,2) M(0,3) M(1,3) M(2,3) M(3,3)

__device__ __forceinline__ float sigm(float x){ return 1.f/(1.f + __expf(-x)); }

// fp32 -> (hi, lo) bf16 pair, 8 contiguous elements
__device__ __forceinline__ void cvt8(const float* p, short8& hi, short8& lo){
  fvec4 a = *(const fvec4*)p;
  fvec4 b = *(const fvec4*)(p + 4);
  #pragma unroll
  for (int j = 0; j < 8; j++){
    float v = (j < 4) ? a[j] : b[j-4];
    __hip_bfloat16 h = __float2bfloat16(v);
    float r = v - __bfloat162float(h);
    hi[j] = (short)__bfloat16_as_ushort(h);
    lo[j] = (short)__bfloat16_as_ushort(__float2bfloat16(r));
  }
}

__device__ __forceinline__ unsigned pack2(float a, float b){
  unsigned ha = __bfloat16_as_ushort(__float2bfloat16(a));
  unsigned hb = __bfloat16_as_ushort(__float2bfloat16(b));
  return ha | (hb << 16);
}
__device__ __forceinline__ unsigned pack2lo(float a, float b){
  float ra = a - __bfloat162float(__float2bfloat16(a));
  float rb = b - __bfloat162float(__float2bfloat16(b));
  return pack2(ra, rb);
}

// agent-scope RELAXED (LLC-coherent, fence-free) 16B load
__device__ __forceinline__ short8 aload16(const short* p){
  union { unsigned long long u[2]; short8 v; } r;
  const unsigned long long* q = (const unsigned long long*)p;
  r.u[0] = __hip_atomic_load(q,     __ATOMIC_RELAXED, SCOPE_AGENT);
  r.u[1] = __hip_atomic_load(q + 1, __ATOMIC_RELAXED, SCOPE_AGENT);
  return r.v;
}

// Wave 0 polls 64 flags (lanes 0..31: layer-0, 32..63: layer-1); waves 1-3
// park at the barrier. Fence-free: data moves via relaxed agent atomics.
__device__ __forceinline__ void poll(const int* fb, int t0, int t1){
  if (threadIdx.x < 64){
    int lid = threadIdx.x;
    int tgt = (lid < 32) ? t0 : t1;
    const int* p = fb + lid;
    int spins = 0;
    for(;;){
      int v = __hip_atomic_load(p, __ATOMIC_RELAXED, SCOPE_AGENT);
      if (__all(v >= tgt)) break;
      if (++spins > (1<<17)) break;                // fail-safe, never hang
      if (spins > 64) __builtin_amdgcn_s_sleep(1);
    }
  }
  __syncthreads();
}

__global__ __launch_bounds__(256, 1) void lstm_kernel(
    const float* __restrict__ x,
    const float* __restrict__ Wih0, const float* __restrict__ Whh0,
    const float* __restrict__ bih0, const float* __restrict__ bhh0,
    const float* __restrict__ Wih1, const float* __restrict__ Whh1,
    const float* __restrict__ bih1, const float* __restrict__ bhh1,
    const float* __restrict__ fcw, const float* __restrict__ fcb,
    float* __restrict__ out,
    short* __restrict__ h1r, short* __restrict__ h2r,
    float* __restrict__ h2last, int* __restrict__ flags)
{
  const int bid   = blockIdx.x;
  const int layer = bid & 1;
  const int bs    = (bid >> 1) & 3;   // batch slice (16 rows)
  const int ns    = bid >> 3;         // H-chunk (16 cols)
  const int tid   = threadIdx.x;
  const int w     = tid >> 6;         // wave = K-quarter owner
  const int l     = tid & 63;
  const int lm    = l & 15;
  const int ke    = (l >> 4) << 3;    // k offset within K=32 step
  const int kw4   = w << 2;           // wave's kk base, H (K=512 -> 16 kk / 4)
  const int kw2   = w << 1;           // wave's kk base, x (K=256 -> 8 kk / 4)

  int* fb     = flags + (bs << 6);
  int* myflag = fb + (layer << 5) + ns;

  // [wave][gate][row][col+pad]: pad 17 kills the 4-way write conflict
  __shared__ float glds[4][4][16][17];

  #define GCOL(g) ((g<<9) + (ns<<4) + lm)     // weight row for gate g
  const int brow = (bs << 4) + lm;            // batch row (A fragment)
  const int bl   = tid >> 4, jj = tid & 15;   // per-thread cell (row, col)
  const int hcolbase = ns << 4;

  float c_reg = 0.f;
  float bia0, bia1, bia2, bia3;
  {
    const float* bi = layer ? bih1 : bih0;
    const float* bh = layer ? bhh1 : bhh0;
    int c0 = (ns<<4) + jj;
    bia0 = bi[c0]      + bh[c0];
    bia1 = bi[512+c0]  + bh[512+c0];
    bia2 = bi[1024+c0] + bh[1024+c0];
    bia3 = bi[1536+c0] + bh[1536+c0];
  }

  // ---- cell update: LDS-reduce wave partials p0..p3 -> c,h -> ring -> flag --
  #define GWR(g) { _Pragma("unroll")                                            \
    for (int r = 0; r < 4; r++) glds[w][g][((l>>4)<<2)+r][lm] = p##g[r]; }
  #define CELLX(SLOTBASE, T, LAST)                                              \
  {                                                                             \
    GWR(0) GWR(1) GWR(2) GWR(3)                                                 \
    __syncthreads();                                                            \
    float gi = glds[0][0][bl][jj]+glds[1][0][bl][jj]+glds[2][0][bl][jj]+glds[3][0][bl][jj]+bia0; \
    float gf = glds[0][1][bl][jj]+glds[1][1][bl][jj]+glds[2][1][bl][jj]+glds[3][1][bl][jj]+bia1; \
    float gg = glds[0][2][bl][jj]+glds[1][2][bl][jj]+glds[2][2][bl][jj]+glds[3][2][bl][jj]+bia2; \
    float go = glds[0][3][bl][jj]+glds[1][3][bl][jj]+glds[2][3][bl][jj]+glds[3][3][bl][jj]+bia3; \
    float cn = sigm(gf)*c_reg + sigm(gi)*tanhf(gg);                             \
    c_reg = cn;                                                                 \
    float hn  = sigm(go)*tanhf(cn);                                             \
    float hn2 = __shfl_down(hn, 1);                                             \
    if (!(jj & 1)){                                                             \
      short* p = (SLOTBASE) + bl*1024 + hcolbase + jj;                          \
      __hip_atomic_store((unsigned*)p,       pack2(hn,hn2),   __ATOMIC_RELAXED, SCOPE_AGENT); \
      __hip_atomic_store((unsigned*)(p+512), pack2lo(hn,hn2), __ATOMIC_RELAXED, SCOPE_AGENT); \
    }                                                                           \
    if (LAST)                                                                   \
      __hip_atomic_store(h2last + (size_t)((bs<<4)+bl)*nH + hcolbase + jj, hn,  \
                         __ATOMIC_RELAXED, SCOPE_AGENT);                        \
    __syncthreads();  /* compiler drains vmcnt(0) before s_barrier */           \
    if (tid == 0)                                                               \
      __hip_atomic_store(myflag, (T), __ATOMIC_RELAXED, SCOPE_AGENT);           \
  }

  if (layer == 0){
    // weights: 4 gates x wave's K-slice (x: 2 kk, h: 4 kk), hi+lo, named vars
    #define DWX(g,i) short8 wxh##g##_##i, wxl##g##_##i;
    GK2(DWX)
    #define LWX(g,i) cvt8(Wih0 + (size_t)GCOL(g)*nD + (kw2+i)*32 + ke, wxh##g##_##i, wxl##g##_##i);
    GK2(LWX)
    #define DWH(g,i) short8 whh##g##_##i, whl##g##_##i;
    GK4(DWH)
    #define LWH(g,i) cvt8(Whh0 + (size_t)GCOL(g)*nH + (kw4+i)*32 + ke, whh##g##_##i, whl##g##_##i);
    GK4(LWH)

    // x-projection for t=0 (wave's K-slice only)
    f32x4 xc0={0,0,0,0}, xc1={0,0,0,0}, xc2={0,0,0,0}, xc3={0,0,0,0};
    {
      const float* xb = x + ((size_t)brow*nT + 0)*nD + ke;
      #define XL0(i) short8 xth##i, xtl##i; cvt8(xb + (kw2+i)*32, xth##i, xtl##i);
      XL0(0) XL0(1)
      #define XM0(g,i) xc##g = MFMA(xth##i, wxh##g##_##i, xc##g);               \
                       xc##g = MFMA(xtl##i, wxh##g##_##i, xc##g);               \
                       xc##g = MFMA(xth##i, wxl##g##_##i, xc##g);
      GK2(XM0)
    }

    for (int t = 0; t < nT; t++){
      poll(fb, t-1, t-8);                       // L0 peers t-1; L1 ring backpressure
      const short* hb = h1r + (size_t)((t+7)&7)*SLOT_ELEMS + brow*1024;
      // wave's K-quarter of h1[t-1]: 8 x 16B (vs 64 in R6)
      #define HLD0(i) short8 vh##i = aload16(hb + (kw4+i)*32 + ke);             \
                      short8 vl##i = aload16(hb + 512 + (kw4+i)*32 + ke);
      K4(HLD0)
      // x-projection for t+1 overlaps the LLC latency of the h loads
      f32x4 xn0={0,0,0,0}, xn1={0,0,0,0}, xn2={0,0,0,0}, xn3={0,0,0,0};
      if (t + 1 < nT){
        const float* xb = x + ((size_t)brow*nT + (t+1))*nD + ke;
        #define XLN(i) short8 nxh##i, nxl##i; cvt8(xb + (kw2+i)*32, nxh##i, nxl##i);
        XLN(0) XLN(1)
        #define XMN(g,i) xn##g = MFMA(nxh##i, wxh##g##_##i, xn##g);             \
                         xn##g = MFMA(nxl##i, wxh##g##_##i, xn##g);             \
                         xn##g = MFMA(nxh##i, wxl##g##_##i, xn##g);
        GK2(XMN)
      }
      // h MFMAs: 4 gates x 4 kk x 3 (hi*hi + lo*hi + hi*lo) = 48/wave
      f32x4 p0 = xc0, p1 = xc1, p2 = xc2, p3 = xc3;
      #define HMM0(g,i) p##g = MFMA(vh##i, whh##g##_##i, p##g);                 \
                        p##g = MFMA(vl##i, whh##g##_##i, p##g);                 \
                        p##g = MFMA(vh##i, whl##g##_##i, p##g);
      GK4(HMM0)
      CELLX(h1r + (size_t)(t&7)*SLOT_ELEMS + (bs<<4)*1024, t, 0)
      xc0 = xn0; xc1 = xn1; xc2 = xn2; xc3 = xn3;
    }
  } else {
    // weights: 4 gates x 4 kk x hi/lo x {Whh1, Wih1} = 64 named short8
    #define DWA(g,i) short8 ahh##g##_##i, ahl##g##_##i;
    GK4(DWA)
    #define LWA(g,i) cvt8(Whh1 + (size_t)GCOL(g)*nH + (kw4+i)*32 + ke, ahh##g##_##i, ahl##g##_##i);
    GK4(LWA)
    #define DWB(g,i) short8 bwh##g##_##i, bwl##g##_##i;
    GK4(DWB)
    #define LWB(g,i) cvt8(Wih1 + (size_t)GCOL(g)*nH + (kw4+i)*32 + ke, bwh##g##_##i, bwl##g##_##i);
    GK4(LWB)

    for (int t = 0; t < nT; t++){
      poll(fb, t, t-1);                         // merged: L0>=t AND own peers>=t-1
      // h2[t-1] part (wave's K-quarter)
      const short* h2b = h2r + (size_t)((t+3)&3)*SLOT_ELEMS + brow*1024;
      #define HLD2(i) short8 u2h##i = aload16(h2b + (kw4+i)*32 + ke);           \
                      short8 u2l##i = aload16(h2b + 512 + (kw4+i)*32 + ke);
      K4(HLD2)
      f32x4 p0={0,0,0,0}, p1={0,0,0,0}, p2={0,0,0,0}, p3={0,0,0,0};
      #define HMM2(g,i) p##g = MFMA(u2h##i, ahh##g##_##i, p##g);                \
                        p##g = MFMA(u2l##i, ahh##g##_##i, p##g);                \
                        p##g = MFMA(u2h##i, ahl##g##_##i, p##g);
      GK4(HMM2)
      // h1[t] part (wave's K-quarter)
      const short* h1b = h1r + (size_t)(t&7)*SLOT_ELEMS + brow*1024;
      #define HLD1(i) short8 u1h##i = aload16(h1b + (kw4+i)*32 + ke);           \
                      short8 u1l##i = aload16(h1b + 512 + (kw4+i)*32 + ke);
      K4(HLD1)
      #define HMM1(g,i) p##g = MFMA(u1h##i, bwh##g##_##i, p##g);                \
                        p##g = MFMA(u1l##i, bwh##g##_##i, p##g);                \
                        p##g = MFMA(u1h##i, bwl##g##_##i, p##g);
      GK4(HMM1)
      CELLX(h2r + (size_t)(t&3)*SLOT_ELEMS + (bs<<4)*1024, t, (t == nT-1))
    }

    // final FC in fp32 VALU: out = h2last @ fc_w^T + fc_b (blocks ns<16)
    if (ns < 16){
      poll(fb, NEG, nT-1);
      const int orow = (bs<<4) + bl;
      const int ocol = (ns<<4) + jj;
      const unsigned long long* hq = (const unsigned long long*)(h2last + (size_t)orow*nH);
      const float* wr = fcw + (size_t)ocol*nH;
      float s0=0.f, s1=0.f, s2=0.f, s3=0.f;
      #pragma unroll 8
      for (int k = 0; k < nH; k += 8){
        union{ unsigned long long u; float f[2]; } q0,q1,q2,q3;
        q0.u = __hip_atomic_load(hq + (k>>1)    , __ATOMIC_RELAXED, SCOPE_AGENT);
        q1.u = __hip_atomic_load(hq + (k>>1) + 1, __ATOMIC_RELAXED, SCOPE_AGENT);
        q2.u = __hip_atomic_load(hq + (k>>1) + 2, __ATOMIC_RELAXED, SCOPE_AGENT);
        q3.u = __hip_atomic_load(hq + (k>>1) + 3, __ATOMIC_RELAXED, SCOPE_AGENT);
        fvec4 w0 = *(const fvec4*)(wr + k);
        fvec4 w1 = *(const fvec4*)(wr + k + 4);
        s0 += q0.f[0]*w0[0] + q0.f[1]*w0[1];
        s1 += q1.f[0]*w0[2] + q1.f[1]*w0[3];
        s2 += q2.f[0]*w1[0] + q2.f[1]*w1[1];
        s3 += q3.f[0]*w1[2] + q3.f[1]*w1[3];
      }
      out[(size_t)orow*nO + ocol] = s0 + s1 + s2 + s3 + fcb[ocol];
    }
  }
}

extern "C" void kernel_launch(void* const* d_in, const int* in_sizes, int n_in,
                              void* d_out, int out_size, void* d_ws, size_t ws_size,
                              hipStream_t stream)
{
  char* ws = (char*)d_ws;
  int*   flags  = (int*)ws;
  short* h1r    = (short*)(ws + RING_OFF);                 // 8 slots
  short* h2r    = h1r + 8ull * SLOT_ELEMS;                 // 4 slots
  float* h2last = (float*)((char*)(h2r + 4ull * SLOT_ELEMS));

  hipMemsetAsync(ws, 0xFF, 4*64*sizeof(int), stream);            // flags = -1
  hipMemsetAsync(h1r + 7ull*SLOT_ELEMS, 0, SLOT_BYTES, stream);  // h1[-1] = 0 (slot 7)
  hipMemsetAsync(h2r + 3ull*SLOT_ELEMS, 0, SLOT_BYTES, stream);  // h2[-1] = 0 (slot 3)

  const float* x    = (const float*)d_in[0];
  const float* Wih0 = (const float*)d_in[1];
  const float* Whh0 = (const float*)d_in[2];
  const float* bih0 = (const float*)d_in[3];
  const float* bhh0 = (const float*)d_in[4];
  const float* Wih1 = (const float*)d_in[5];
  const float* Whh1 = (const float*)d_in[6];
  const float* bih1 = (const float*)d_in[7];
  const float* bhh1 = (const float*)d_in[8];
  const float* fcw  = (const float*)d_in[9];
  const float* fcb  = (const float*)d_in[10];
  float* out = (float*)d_out;

  lstm_kernel<<<256, 256, 0, stream>>>(x, Wih0, Whh0, bih0, bhh0,
      Wih1, Whh1, bih1, bhh1, fcw, fcb, out, h1r, h2r, h2last, flags);
}